// Round 1
// baseline (1885.667 us; speedup 1.0000x reference)
//
#include <hip/hip_runtime.h>
#include <hip/hip_bf16.h>
#include <math.h>

// Problem shape (fixed by reference setup_inputs): B=8, L=2048, D=1024, n=16, d=64
#define BATCH 8
#define SEQL  2048
#define DIM   1024
#define NHEAD 16
#define HDIM  64
#define MROWS (BATCH * SEQL)   // 16384

#define BM 128
#define BN 128
#define BK 8

// C[m,n] = sum_k A[m,k] * Bw[n,k]  (+bias[n]) (optional sigmoid)
template<int DO_SIG>
__global__ __launch_bounds__(256) void gemm_bt(const float* __restrict__ A,
                                               const float* __restrict__ Bw,
                                               const float* __restrict__ bias,
                                               float* __restrict__ C,
                                               int M, int N, int K)
{
    __shared__ float As[BK][BM + 4];
    __shared__ float Bs[BK][BN + 4];

    const int tid = threadIdx.x;
    const int bm = blockIdx.y * BM;
    const int bn = blockIdx.x * BN;
    const int tx = tid & 15;        // 0..15 -> col group
    const int ty = tid >> 4;        // 0..15 -> row group

    float acc[8][8];
    #pragma unroll
    for (int i = 0; i < 8; ++i)
        #pragma unroll
        for (int j = 0; j < 8; ++j) acc[i][j] = 0.f;

    // Tile loading: 128 rows x 8 k, 1024 floats per matrix, 256 threads -> float4 each
    const int lr = tid >> 1;          // 0..127 row in tile
    const int lc = (tid & 1) * 4;     // 0 or 4 within BK

    const float* Ap = A + (size_t)(bm + lr) * K + lc;
    const float* Bp = Bw + (size_t)(bn + lr) * K + lc;

    for (int k0 = 0; k0 < K; k0 += BK) {
        const float4 a4 = *(const float4*)(Ap + k0);
        const float4 b4 = *(const float4*)(Bp + k0);
        As[lc + 0][lr] = a4.x; As[lc + 1][lr] = a4.y;
        As[lc + 2][lr] = a4.z; As[lc + 3][lr] = a4.w;
        Bs[lc + 0][lr] = b4.x; Bs[lc + 1][lr] = b4.y;
        Bs[lc + 2][lr] = b4.z; Bs[lc + 3][lr] = b4.w;
        __syncthreads();

        #pragma unroll
        for (int kk = 0; kk < BK; ++kk) {
            float a[8], b[8];
            #pragma unroll
            for (int i = 0; i < 8; ++i) a[i] = As[kk][ty * 8 + i];
            #pragma unroll
            for (int j = 0; j < 8; ++j) b[j] = Bs[kk][tx * 8 + j];
            #pragma unroll
            for (int i = 0; i < 8; ++i)
                #pragma unroll
                for (int j = 0; j < 8; ++j)
                    acc[i][j] = fmaf(a[i], b[j], acc[i][j]);
        }
        __syncthreads();
    }

    // epilogue: 8 rows x 8 cols per thread, two float4 stores per row
    #pragma unroll
    for (int i = 0; i < 8; ++i) {
        const int row = bm + ty * 8 + i;
        const int col0 = bn + tx * 8;
        float v[8];
        #pragma unroll
        for (int j = 0; j < 8; ++j) {
            float t = acc[i][j];
            if (bias) t += bias[col0 + j];
            if (DO_SIG) t = 1.f / (1.f + __expf(-t));
            v[j] = t;
        }
        float* cp = C + (size_t)row * N + col0;
        *(float4*)(cp + 0) = make_float4(v[0], v[1], v[2], v[3]);
        *(float4*)(cp + 4) = make_float4(v[4], v[5], v[6], v[7]);
    }
}

// One wave (64 threads) per (batch, head) sequence; thread j owns dim j.
// Reads k from Kv and g from Gv, writes h (the scan output o) in-place into Kv.
__global__ __launch_bounds__(64) void scan_kernel(float* __restrict__ Kv,
                                                  const float* __restrict__ Gv)
{
    const int b  = blockIdx.x / NHEAD;
    const int hh = blockIdx.x % NHEAD;
    const int j  = threadIdx.x;

    size_t off = (size_t)b * SEQL * DIM + (size_t)hh * HDIM + j;
    float h = 0.f;

    // prefetch first step
    float kn = Kv[off];
    float gn = Gv[off];

    for (int t = 0; t < SEQL; ++t) {
        const float kc = kn, gc = gn;
        const size_t noff = off + DIM;
        if (t + 1 < SEQL) {         // prefetch next step while computing this one
            kn = Kv[noff];
            gn = Gv[noff];
        }
        float s = h * h;
        #pragma unroll
        for (int m = 32; m >= 1; m >>= 1) s += __shfl_xor(s, m, 64);
        const float rms = sqrtf(s) * 0.125f;      // * 1/sqrt(64)
        const float hn = h / (rms + 1e-5f) * gc + kc;
        Kv[off] = hn;
        h = hn;
        off = noff;
    }
}

extern "C" void kernel_launch(void* const* d_in, const int* in_sizes, int n_in,
                              void* d_out, int out_size, void* d_ws, size_t ws_size,
                              hipStream_t stream) {
    const float* x    = (const float*)d_in[0];   // [B,L,D]
    const float* Wk   = (const float*)d_in[1];   // [D,D]
    const float* Wkg  = (const float*)d_in[2];   // [D,D]
    const float* bkg  = (const float*)d_in[3];   // [D]
    const float* Wout = (const float*)d_in[4];   // [D,D]
    float* out = (float*)d_out;                  // [B,L,D]

    float* Kbuf = (float*)d_ws;                        // [B,L,D] = 64 MB
    float* Gbuf = Kbuf + (size_t)MROWS * DIM;          // [B,L,D] = 64 MB

    const dim3 gblk(256);
    const dim3 ggrid(DIM / BN, MROWS / BM);            // (8, 128)

    // k = x @ Wk.T
    gemm_bt<0><<<ggrid, gblk, 0, stream>>>(x, Wk, nullptr, Kbuf, MROWS, DIM, DIM);
    // g = sigmoid(x @ Wkg.T + bkg)
    gemm_bt<1><<<ggrid, gblk, 0, stream>>>(x, Wkg, bkg, Gbuf, MROWS, DIM, DIM);
    // sequential scan, o overwrites Kbuf
    scan_kernel<<<dim3(BATCH * NHEAD), dim3(64), 0, stream>>>(Kbuf, Gbuf);
    // out = o @ Wout.T
    gemm_bt<0><<<ggrid, gblk, 0, stream>>>(Kbuf, Wout, nullptr, out, MROWS, DIM, DIM);
}

// Round 3
// 1749.374 us; speedup vs baseline: 1.0779x; 1.0779x over previous
//
#include <hip/hip_runtime.h>
#include <hip/hip_bf16.h>
#include <math.h>

// Problem shape (fixed by reference setup_inputs): B=8, L=2048, D=1024, n=16, d=64
#define BATCH 8
#define SEQL  2048
#define DIM   1024
#define NHEAD 16
#define HDIM  64
#define MROWS (BATCH * SEQL)   // 16384

#define BM 128
#define BN 128
#define BK 8

// C[m,n] = sum_k A[m,k] * Bw[n,k]  (+bias[n]) (optional sigmoid)
template<int DO_SIG>
__global__ __launch_bounds__(256) void gemm_bt(const float* __restrict__ A,
                                               const float* __restrict__ Bw,
                                               const float* __restrict__ bias,
                                               float* __restrict__ C,
                                               int M, int N, int K)
{
    __shared__ float As[BK][BM + 4];
    __shared__ float Bs[BK][BN + 4];

    const int tid = threadIdx.x;
    const int bm = blockIdx.y * BM;
    const int bn = blockIdx.x * BN;
    const int tx = tid & 15;        // 0..15 -> col group
    const int ty = tid >> 4;        // 0..15 -> row group

    float acc[8][8];
    #pragma unroll
    for (int i = 0; i < 8; ++i)
        #pragma unroll
        for (int j = 0; j < 8; ++j) acc[i][j] = 0.f;

    // Tile loading: 128 rows x 8 k, 1024 floats per matrix, 256 threads -> float4 each
    const int lr = tid >> 1;          // 0..127 row in tile
    const int lc = (tid & 1) * 4;     // 0 or 4 within BK

    const float* Ap = A + (size_t)(bm + lr) * K + lc;
    const float* Bp = Bw + (size_t)(bn + lr) * K + lc;

    for (int k0 = 0; k0 < K; k0 += BK) {
        const float4 a4 = *(const float4*)(Ap + k0);
        const float4 b4 = *(const float4*)(Bp + k0);
        As[lc + 0][lr] = a4.x; As[lc + 1][lr] = a4.y;
        As[lc + 2][lr] = a4.z; As[lc + 3][lr] = a4.w;
        Bs[lc + 0][lr] = b4.x; Bs[lc + 1][lr] = b4.y;
        Bs[lc + 2][lr] = b4.z; Bs[lc + 3][lr] = b4.w;
        __syncthreads();

        #pragma unroll
        for (int kk = 0; kk < BK; ++kk) {
            float a[8], b[8];
            #pragma unroll
            for (int i = 0; i < 8; ++i) a[i] = As[kk][ty * 8 + i];
            #pragma unroll
            for (int j = 0; j < 8; ++j) b[j] = Bs[kk][tx * 8 + j];
            #pragma unroll
            for (int i = 0; i < 8; ++i)
                #pragma unroll
                for (int j = 0; j < 8; ++j)
                    acc[i][j] = fmaf(a[i], b[j], acc[i][j]);
        }
        __syncthreads();
    }

    // epilogue: 8 rows x 8 cols per thread, two float4 stores per row
    #pragma unroll
    for (int i = 0; i < 8; ++i) {
        const int row = bm + ty * 8 + i;
        const int col0 = bn + tx * 8;
        float v[8];
        #pragma unroll
        for (int j = 0; j < 8; ++j) {
            float t = acc[i][j];
            if (bias) t += bias[col0 + j];
            if (DO_SIG) t = 1.f / (1.f + __expf(-t));
            v[j] = t;
        }
        float* cp = C + (size_t)row * N + col0;
        *(float4*)(cp + 0) = make_float4(v[0], v[1], v[2], v[3]);
        *(float4*)(cp + 4) = make_float4(v[4], v[5], v[6], v[7]);
    }
}

// DPP-based add of a cross-lane permuted value (VALU latency, not LDS).
// CTRL must be a compile-time constant -> template parameter.
template<int CTRL>
__device__ __forceinline__ float dpp_add_f(float s) {
    int t = __builtin_amdgcn_update_dpp(0, __float_as_int(s), CTRL, 0xF, 0xF, true);
    return s + __int_as_float(t);
}

// One wave (64 threads) per (batch, head) sequence; thread j owns dim j.
// Reads k from Kv and g from Gv, writes h (the scan output o) in-place into Kv.
// Wave-sum of h*h via DPP chain (quad_perm/mirrors/bcast) + readlane 63:
// dependent-chain ~100 cycles/step vs ~760 with ds_swizzle-based __shfl_xor.
__global__ __launch_bounds__(64) void scan_kernel(float* __restrict__ Kv,
                                                  const float* __restrict__ Gv)
{
    const int b  = blockIdx.x / NHEAD;
    const int hh = blockIdx.x % NHEAD;
    const int j  = threadIdx.x;

    size_t off = (size_t)b * SEQL * DIM + (size_t)hh * HDIM + j;
    float h = 0.f;

    // prefetch first step
    float kn = Kv[off];
    float gn = Gv[off];

    for (int t = 0; t < SEQL; ++t) {
        const float kc = kn, gc = gn;
        const size_t noff = off + DIM;
        if (t + 1 < SEQL) {         // prefetch next step while computing this one
            kn = Kv[noff];
            gn = Gv[noff];
        }
        float s = h * h;
        s = dpp_add_f<0xB1>(s);     // quad_perm [1,0,3,2]  (xor 1)
        s = dpp_add_f<0x4E>(s);     // quad_perm [2,3,0,1]  (xor 2)
        s = dpp_add_f<0x141>(s);    // row_half_mirror      (xor 4)
        s = dpp_add_f<0x140>(s);    // row_mirror           (xor 8)
        s = dpp_add_f<0x142>(s);    // row_bcast15: row n+1 += row n
        s = dpp_add_f<0x143>(s);    // row_bcast31: upper half += lane31; lane63 = total
        const float tot = __int_as_float(__builtin_amdgcn_readlane(__float_as_int(s), 63));
        const float rms = __builtin_amdgcn_sqrtf(tot) * 0.125f;   // * 1/sqrt(64)
        const float inv = __builtin_amdgcn_rcpf(rms + 1e-5f);     // 1-ulp rcp, plenty for threshold
        const float hn = fmaf(h * gc, inv, kc);
        Kv[off] = hn;
        h = hn;
        off = noff;
    }
}

extern "C" void kernel_launch(void* const* d_in, const int* in_sizes, int n_in,
                              void* d_out, int out_size, void* d_ws, size_t ws_size,
                              hipStream_t stream) {
    const float* x    = (const float*)d_in[0];   // [B,L,D]
    const float* Wk   = (const float*)d_in[1];   // [D,D]
    const float* Wkg  = (const float*)d_in[2];   // [D,D]
    const float* bkg  = (const float*)d_in[3];   // [D]
    const float* Wout = (const float*)d_in[4];   // [D,D]
    float* out = (float*)d_out;                  // [B,L,D]

    float* Kbuf = (float*)d_ws;                        // [B,L,D] = 64 MB
    float* Gbuf = Kbuf + (size_t)MROWS * DIM;          // [B,L,D] = 64 MB

    const dim3 gblk(256);
    const dim3 ggrid(DIM / BN, MROWS / BM);            // (8, 128)

    // k = x @ Wk.T
    gemm_bt<0><<<ggrid, gblk, 0, stream>>>(x, Wk, nullptr, Kbuf, MROWS, DIM, DIM);
    // g = sigmoid(x @ Wkg.T + bkg)
    gemm_bt<1><<<ggrid, gblk, 0, stream>>>(x, Wkg, bkg, Gbuf, MROWS, DIM, DIM);
    // sequential scan, o overwrites Kbuf
    scan_kernel<<<dim3(BATCH * NHEAD), dim3(64), 0, stream>>>(Kbuf, Gbuf);
    // out = o @ Wout.T
    gemm_bt<0><<<ggrid, gblk, 0, stream>>>(Kbuf, Wout, nullptr, out, MROWS, DIM, DIM);
}

// Round 4
// 1368.445 us; speedup vs baseline: 1.3780x; 1.2784x over previous
//
#include <hip/hip_runtime.h>
#include <hip/hip_bf16.h>
#include <math.h>

// Problem shape (fixed by reference setup_inputs): B=8, L=2048, D=1024, n=16, d=64
#define BATCH 8
#define SEQL  2048
#define DIM   1024
#define NHEAD 16
#define HDIM  64
#define MROWS (BATCH * SEQL)   // 16384

#define BM 128
#define BN 128
#define BK 8

// C[m,n] = sum_k A[m,k] * Bw[n,k]  (+bias[n]) (optional sigmoid)
template<int DO_SIG>
__global__ __launch_bounds__(256) void gemm_bt(const float* __restrict__ A,
                                               const float* __restrict__ Bw,
                                               const float* __restrict__ bias,
                                               float* __restrict__ C,
                                               int M, int N, int K)
{
    __shared__ float As[BK][BM + 4];
    __shared__ float Bs[BK][BN + 4];

    const int tid = threadIdx.x;
    const int bm = blockIdx.y * BM;
    const int bn = blockIdx.x * BN;
    const int tx = tid & 15;        // 0..15 -> col group
    const int ty = tid >> 4;        // 0..15 -> row group

    float acc[8][8];
    #pragma unroll
    for (int i = 0; i < 8; ++i)
        #pragma unroll
        for (int j = 0; j < 8; ++j) acc[i][j] = 0.f;

    // Tile loading: 128 rows x 8 k, 1024 floats per matrix, 256 threads -> float4 each
    const int lr = tid >> 1;          // 0..127 row in tile
    const int lc = (tid & 1) * 4;     // 0 or 4 within BK

    const float* Ap = A + (size_t)(bm + lr) * K + lc;
    const float* Bp = Bw + (size_t)(bn + lr) * K + lc;

    for (int k0 = 0; k0 < K; k0 += BK) {
        const float4 a4 = *(const float4*)(Ap + k0);
        const float4 b4 = *(const float4*)(Bp + k0);
        As[lc + 0][lr] = a4.x; As[lc + 1][lr] = a4.y;
        As[lc + 2][lr] = a4.z; As[lc + 3][lr] = a4.w;
        Bs[lc + 0][lr] = b4.x; Bs[lc + 1][lr] = b4.y;
        Bs[lc + 2][lr] = b4.z; Bs[lc + 3][lr] = b4.w;
        __syncthreads();

        #pragma unroll
        for (int kk = 0; kk < BK; ++kk) {
            float a[8], b[8];
            #pragma unroll
            for (int i = 0; i < 8; ++i) a[i] = As[kk][ty * 8 + i];
            #pragma unroll
            for (int j = 0; j < 8; ++j) b[j] = Bs[kk][tx * 8 + j];
            #pragma unroll
            for (int i = 0; i < 8; ++i)
                #pragma unroll
                for (int j = 0; j < 8; ++j)
                    acc[i][j] = fmaf(a[i], b[j], acc[i][j]);
        }
        __syncthreads();
    }

    // epilogue: 8 rows x 8 cols per thread, two float4 stores per row
    #pragma unroll
    for (int i = 0; i < 8; ++i) {
        const int row = bm + ty * 8 + i;
        const int col0 = bn + tx * 8;
        float v[8];
        #pragma unroll
        for (int j = 0; j < 8; ++j) {
            float t = acc[i][j];
            if (bias) t += bias[col0 + j];
            if (DO_SIG) t = 1.f / (1.f + __expf(-t));
            v[j] = t;
        }
        float* cp = C + (size_t)row * N + col0;
        *(float4*)(cp + 0) = make_float4(v[0], v[1], v[2], v[3]);
        *(float4*)(cp + 4) = make_float4(v[4], v[5], v[6], v[7]);
    }
}

// DPP-based add of a cross-lane permuted value (VALU latency, not LDS).
// CTRL must be a compile-time constant -> template parameter.
template<int CTRL>
__device__ __forceinline__ float dpp_add_f(float s) {
    int t = __builtin_amdgcn_update_dpp(0, __float_as_int(s), CTRL, 0xF, 0xF, true);
    return s + __int_as_float(t);
}

#define PF 8   // prefetch depth (steps ahead); 8 * ~110cy chain covers ~900cy HBM latency

// One wave (64 threads) per (batch, head) sequence; thread j owns dim j.
// Reads k from Kv and g from Gv, writes h (the scan output o) in-place into Kv.
// Wave-sum of h*h via DPP chain; k/g prefetched PF steps ahead in a register
// ring (static indices via full unroll) so global-load latency is off the
// critical path.
__global__ __launch_bounds__(64) void scan_kernel(float* __restrict__ Kv,
                                                  const float* __restrict__ Gv)
{
    const int b  = blockIdx.x / NHEAD;
    const int hh = blockIdx.x % NHEAD;
    const int j  = threadIdx.x;

    const size_t base = (size_t)b * SEQL * DIM + (size_t)hh * HDIM + j;
    float h = 0.f;

    float kb[PF], gb[PF];
    #pragma unroll
    for (int u = 0; u < PF; ++u) {
        kb[u] = Kv[base + (size_t)u * DIM];
        gb[u] = Gv[base + (size_t)u * DIM];
    }

    size_t off = base;

    #define SCAN_STEP(kc, gc)                                                          \
        do {                                                                           \
            float s = h * h;                                                           \
            s = dpp_add_f<0xB1>(s);   /* quad_perm xor1 */                             \
            s = dpp_add_f<0x4E>(s);   /* quad_perm xor2 */                             \
            s = dpp_add_f<0x141>(s);  /* row_half_mirror (xor4) */                     \
            s = dpp_add_f<0x140>(s);  /* row_mirror (xor8) */                          \
            s = dpp_add_f<0x142>(s);  /* row_bcast15 */                                \
            s = dpp_add_f<0x143>(s);  /* row_bcast31: lane63 = total */                \
            const float tot = __int_as_float(                                          \
                __builtin_amdgcn_readlane(__float_as_int(s), 63));                     \
            const float rms = __builtin_amdgcn_sqrtf(tot) * 0.125f;                    \
            const float inv = __builtin_amdgcn_rcpf(rms + 1e-5f);                      \
            const float hn  = fmaf(h * (gc), inv, (kc));                               \
            Kv[off] = hn;                                                              \
            h = hn;                                                                    \
            off += DIM;                                                                \
        } while (0)

    // main: blocks of PF steps, each consumes ring slot u and refills it PF ahead
    int t0;
    for (t0 = 0; t0 + PF < SEQL; t0 += PF) {
        #pragma unroll
        for (int u = 0; u < PF; ++u) {
            const float kc = kb[u], gc = gb[u];
            // refill slot u with step (t0 + u + PF); independent of h-chain
            const size_t poff = off + (size_t)PF * DIM;
            kb[u] = Kv[poff];
            gb[u] = Gv[poff];
            SCAN_STEP(kc, gc);
        }
    }
    // tail: last PF steps, no refill
    #pragma unroll
    for (int u = 0; u < PF; ++u) {
        const float kc = kb[u], gc = gb[u];
        SCAN_STEP(kc, gc);
    }
    #undef SCAN_STEP
}

extern "C" void kernel_launch(void* const* d_in, const int* in_sizes, int n_in,
                              void* d_out, int out_size, void* d_ws, size_t ws_size,
                              hipStream_t stream) {
    const float* x    = (const float*)d_in[0];   // [B,L,D]
    const float* Wk   = (const float*)d_in[1];   // [D,D]
    const float* Wkg  = (const float*)d_in[2];   // [D,D]
    const float* bkg  = (const float*)d_in[3];   // [D]
    const float* Wout = (const float*)d_in[4];   // [D,D]
    float* out = (float*)d_out;                  // [B,L,D]

    float* Kbuf = (float*)d_ws;                        // [B,L,D] = 64 MB
    float* Gbuf = Kbuf + (size_t)MROWS * DIM;          // [B,L,D] = 64 MB

    const dim3 gblk(256);
    const dim3 ggrid(DIM / BN, MROWS / BM);            // (8, 128)

    // k = x @ Wk.T
    gemm_bt<0><<<ggrid, gblk, 0, stream>>>(x, Wk, nullptr, Kbuf, MROWS, DIM, DIM);
    // g = sigmoid(x @ Wkg.T + bkg)
    gemm_bt<1><<<ggrid, gblk, 0, stream>>>(x, Wkg, bkg, Gbuf, MROWS, DIM, DIM);
    // sequential scan, o overwrites Kbuf
    scan_kernel<<<dim3(BATCH * NHEAD), dim3(64), 0, stream>>>(Kbuf, Gbuf);
    // out = o @ Wout.T
    gemm_bt<0><<<ggrid, gblk, 0, stream>>>(Kbuf, Wout, nullptr, out, MROWS, DIM, DIM);
}

// Round 5
// 359.081 us; speedup vs baseline: 5.2514x; 3.8110x over previous
//
#include <hip/hip_runtime.h>
#include <hip/hip_bf16.h>
#include <math.h>

// Problem shape (fixed by reference setup_inputs): B=8, L=2048, D=1024, n=16, d=64
#define BATCH 8
#define SEQL  2048
#define DIM   1024
#define NHEAD 16
#define HDIM  64
#define MROWS (BATCH * SEQL)   // 16384

typedef _Float16 f16;
typedef _Float16 f16x8 __attribute__((ext_vector_type(8)));
typedef float f32x4 __attribute__((ext_vector_type(4)));

// ---------------------------------------------------------------------------
// fp32 -> f16 convert, 8 elems/thread, vectorized
__global__ __launch_bounds__(256) void cvt_f32_f16(const float* __restrict__ in,
                                                   f16* __restrict__ out, int n8)
{
    const int i = blockIdx.x * 256 + threadIdx.x;
    if (i >= n8) return;
    const float4* p = (const float4*)in + (size_t)i * 2;
    const float4 a = p[0], b = p[1];
    f16x8 v;
    v[0] = (f16)a.x; v[1] = (f16)a.y; v[2] = (f16)a.z; v[3] = (f16)a.w;
    v[4] = (f16)b.x; v[5] = (f16)b.y; v[6] = (f16)b.z; v[7] = (f16)b.w;
    *(f16x8*)(out + (size_t)i * 8) = v;
}

// ---------------------------------------------------------------------------
// f16 MFMA GEMM, m97 structure: C[m,n] = sum_k A[m,k]*Bw[n,k] (+bias, sigmoid)
// 128x128 tile, BK=64, 4 waves (2x2), 64x64 per wave, 16x16x32 MFMA,
// global_load_lds width-16 staging, single-buffer 2-barrier K-loop.
// A, Bw are f16 row-major with K contiguous (B^T GEMM). M=16384, N=K=1024.
template<int DO_SIG, int OUT_F16>
__global__ __launch_bounds__(256) void gemm_f16(const f16* __restrict__ A,
                                                const f16* __restrict__ Bw,
                                                const float* __restrict__ bias,
                                                void* __restrict__ Cout)
{
    constexpr int K = DIM, N = DIM;
    __shared__ f16 Alds[128 * 64];
    __shared__ f16 Blds[128 * 64];

    const int tid = threadIdx.x;
    const int w = tid >> 6;       // wave 0..3
    const int l = tid & 63;

    // bijective XCD swizzle (nwg = 1024, % 8 == 0): XCD i gets a contiguous
    // chunk of logical tiles -> the 8 bn-blocks sharing an A panel co-reside.
    const int cpx = gridDim.x >> 3;                       // 128
    const int lt  = (blockIdx.x & 7) * cpx + (blockIdx.x >> 3);
    const int bm  = (lt >> 3) * 128;                      // 128 row panels
    const int bn  = (lt & 7) * 128;                       // 8 col panels

    // staging geometry: per wave-call, 64 lanes x 16B = 1KB = 8 rows of BK=64
    const int sr = w * 32 + (l >> 3);       // +i*8 -> row in tile
    const int sc = (l & 7) * 8;             // col in tile
    const size_t gaA = (size_t)(bm + sr) * K + sc;
    const size_t gaB = (size_t)(bn + sr) * K + sc;
    const int le = w * 2048 + l * 8;        // +i*512 -> LDS elem offset (linear)

    const int wr = (w >> 1) * 64;           // wave's output sub-tile origin
    const int wc = (w & 1) * 64;
    const int lrow = l & 15;                // fragment row/col
    const int lko  = (l >> 4) * 8;          // fragment k-offset within 32

    f32x4 acc[4][4];
    #pragma unroll
    for (int mi = 0; mi < 4; ++mi)
        #pragma unroll
        for (int ni = 0; ni < 4; ++ni) acc[mi][ni] = (f32x4){0.f, 0.f, 0.f, 0.f};

    for (int k0 = 0; k0 < K; k0 += 64) {
        __syncthreads();   // previous tile fully consumed before overwrite
        #pragma unroll
        for (int i = 0; i < 4; ++i)
            __builtin_amdgcn_global_load_lds(
                (const __attribute__((address_space(1))) void*)(A + gaA + (size_t)(i * 8) * K + k0),
                (__attribute__((address_space(3))) void*)(Alds + le + i * 512), 16, 0, 0);
        #pragma unroll
        for (int i = 0; i < 4; ++i)
            __builtin_amdgcn_global_load_lds(
                (const __attribute__((address_space(1))) void*)(Bw + gaB + (size_t)(i * 8) * K + k0),
                (__attribute__((address_space(3))) void*)(Blds + le + i * 512), 16, 0, 0);
        __syncthreads();   // compiler drains vmcnt(0) before this barrier

        #pragma unroll
        for (int ks = 0; ks < 2; ++ks) {
            f16x8 af[4], bf[4];
            #pragma unroll
            for (int mi = 0; mi < 4; ++mi)
                af[mi] = *(const f16x8*)(Alds + (wr + mi * 16 + lrow) * 64 + ks * 32 + lko);
            #pragma unroll
            for (int ni = 0; ni < 4; ++ni)
                bf[ni] = *(const f16x8*)(Blds + (wc + ni * 16 + lrow) * 64 + ks * 32 + lko);
            #pragma unroll
            for (int mi = 0; mi < 4; ++mi)
                #pragma unroll
                for (int ni = 0; ni < 4; ++ni)
                    acc[mi][ni] = __builtin_amdgcn_mfma_f32_16x16x32_f16(
                        af[mi], bf[ni], acc[mi][ni], 0, 0, 0);
        }
    }

    // epilogue: C/D layout col = l&15, row = (l>>4)*4 + reg (m89-verified)
    const int orow = (l >> 4) * 4;
    const int ocol = l & 15;
    #pragma unroll
    for (int mi = 0; mi < 4; ++mi) {
        #pragma unroll
        for (int ni = 0; ni < 4; ++ni) {
            const int col = bn + wc + ni * 16 + ocol;
            const float bsv = DO_SIG ? bias[col] : 0.f;
            #pragma unroll
            for (int r = 0; r < 4; ++r) {
                const int row = bm + wr + mi * 16 + orow + r;
                float v = acc[mi][ni][r];
                if (DO_SIG) { v += bsv; v = 1.f / (1.f + __expf(-v)); }
                if (OUT_F16) ((f16*)Cout)[(size_t)row * N + col] = (f16)v;
                else         ((float*)Cout)[(size_t)row * N + col] = v;
            }
        }
    }
}

// ---------------------------------------------------------------------------
// DPP-based cross-lane add (VALU latency, not LDS). CTRL is compile-time.
template<int CTRL>
__device__ __forceinline__ float dpp_add_f(float s) {
    int t = __builtin_amdgcn_update_dpp(0, __float_as_int(s), CTRL, 0xF, 0xF, true);
    return s + __int_as_float(t);
}

#define PF 8   // prefetch depth; 8 * ~110cy chain covers ~900cy HBM latency

// One wave per (batch, head) sequence; thread j owns dim j. f16 in/out,
// fp32 state. k/g prefetched PF steps ahead in a fully-unrolled register ring.
__global__ __launch_bounds__(64) void scan_kernel(f16* __restrict__ Kv,
                                                  const f16* __restrict__ Gv)
{
    const int b  = blockIdx.x / NHEAD;
    const int hh = blockIdx.x % NHEAD;
    const int j  = threadIdx.x;

    const size_t base = (size_t)b * SEQL * DIM + (size_t)hh * HDIM + j;
    float h = 0.f;

    f16 kb[PF], gb[PF];
    #pragma unroll
    for (int u = 0; u < PF; ++u) {
        kb[u] = Kv[base + (size_t)u * DIM];
        gb[u] = Gv[base + (size_t)u * DIM];
    }

    size_t off = base;

    #define SCAN_STEP(kc, gc)                                                          \
        do {                                                                           \
            float s = h * h;                                                           \
            s = dpp_add_f<0xB1>(s);   /* quad_perm xor1 */                             \
            s = dpp_add_f<0x4E>(s);   /* quad_perm xor2 */                             \
            s = dpp_add_f<0x141>(s);  /* row_half_mirror (xor4) */                     \
            s = dpp_add_f<0x140>(s);  /* row_mirror (xor8) */                          \
            s = dpp_add_f<0x142>(s);  /* row_bcast15 */                                \
            s = dpp_add_f<0x143>(s);  /* row_bcast31: lane63 = total */                \
            const float tot = __int_as_float(                                          \
                __builtin_amdgcn_readlane(__float_as_int(s), 63));                     \
            const float rms = __builtin_amdgcn_sqrtf(tot) * 0.125f;                    \
            const float inv = __builtin_amdgcn_rcpf(rms + 1e-5f);                      \
            const float hn  = fmaf(h * (gc), inv, (kc));                               \
            Kv[off] = (f16)hn;                                                         \
            h = hn;                                                                    \
            off += DIM;                                                                \
        } while (0)

    for (int t0 = 0; t0 + PF < SEQL; t0 += PF) {
        #pragma unroll
        for (int u = 0; u < PF; ++u) {
            const float kc = (float)kb[u], gc = (float)gb[u];
            const size_t poff = off + (size_t)PF * DIM;   // refill PF ahead
            kb[u] = Kv[poff];
            gb[u] = Gv[poff];
            SCAN_STEP(kc, gc);
        }
    }
    #pragma unroll
    for (int u = 0; u < PF; ++u) {
        const float kc = (float)kb[u], gc = (float)gb[u];
        SCAN_STEP(kc, gc);
    }
    #undef SCAN_STEP
}

// ---------------------------------------------------------------------------
extern "C" void kernel_launch(void* const* d_in, const int* in_sizes, int n_in,
                              void* d_out, int out_size, void* d_ws, size_t ws_size,
                              hipStream_t stream) {
    const float* x    = (const float*)d_in[0];   // [B,L,D]
    const float* Wk   = (const float*)d_in[1];   // [D,D]
    const float* Wkg  = (const float*)d_in[2];   // [D,D]
    const float* bkg  = (const float*)d_in[3];   // [D]
    const float* Wout = (const float*)d_in[4];   // [D,D]
    float* out = (float*)d_out;                  // [B,L,D] fp32

    // workspace: all f16. 3*32MB + 3*2MB = 102MB
    f16* xh    = (f16*)d_ws;                         // [M, D]
    f16* Kh    = xh    + (size_t)MROWS * DIM;        // [M, D] (scan in-place)
    f16* Gh    = Kh    + (size_t)MROWS * DIM;        // [M, D]
    f16* Wkh   = Gh    + (size_t)MROWS * DIM;        // [D, D]
    f16* Wkgh  = Wkh   + (size_t)DIM * DIM;
    f16* Wouth = Wkgh  + (size_t)DIM * DIM;

    // converts
    const int nx8 = MROWS * DIM / 8;                 // 2,097,152
    const int nw8 = DIM * DIM / 8;                   // 131,072
    cvt_f32_f16<<<dim3(nx8 / 256), dim3(256), 0, stream>>>(x, xh, nx8);
    cvt_f32_f16<<<dim3(nw8 / 256), dim3(256), 0, stream>>>(Wk, Wkh, nw8);
    cvt_f32_f16<<<dim3(nw8 / 256), dim3(256), 0, stream>>>(Wkg, Wkgh, nw8);
    cvt_f32_f16<<<dim3(nw8 / 256), dim3(256), 0, stream>>>(Wout, Wouth, nw8);

    const dim3 gblk(256);
    const dim3 ggrid((MROWS / 128) * (DIM / 128));   // 1024 blocks

    // k = x @ Wk.T   (f16 out)
    gemm_f16<0, 1><<<ggrid, gblk, 0, stream>>>(xh, Wkh, nullptr, Kh);
    // g = sigmoid(x @ Wkg.T + bkg)   (f16 out)
    gemm_f16<1, 1><<<ggrid, gblk, 0, stream>>>(xh, Wkgh, bkg, Gh);
    // sequential scan, o overwrites Kh (f16)
    scan_kernel<<<dim3(BATCH * NHEAD), dim3(64), 0, stream>>>(Kh, Gh);
    // out = o @ Wout.T   (fp32 out)
    gemm_f16<0, 0><<<ggrid, gblk, 0, stream>>>(Kh, Wouth, nullptr, out);
}